// Round 17
// baseline (777.245 us; speedup 1.0000x reference)
//
#include <hip/hip_runtime.h>

#define DIM 1536
#define NH 12
#define HD 128
#define LQ 3200
#define LKV 512
#define FFN 8960

typedef __attribute__((ext_vector_type(8))) short bf16x8;
typedef __attribute__((ext_vector_type(4))) float f32x4;
typedef __attribute__((ext_vector_type(4))) unsigned short u16x4;

__device__ inline unsigned short f2b(float f){
  union { float f; unsigned u; } x; x.f = f;
  unsigned r = (x.u + 0x7FFFu + ((x.u >> 16) & 1u)) >> 16;
  return (unsigned short)r;
}
__device__ inline float b2f(unsigned short u){
  union { unsigned u; float f; } x; x.u = ((unsigned)u) << 16; return x.f;
}
__device__ inline unsigned pack2(float a, float b){
  return (unsigned)f2b(a) | ((unsigned)f2b(b) << 16);
}
__device__ inline f32x4 mfma16(bf16x8 a, bf16x8 b, f32x4 c){
  return __builtin_amdgcn_mfma_f32_16x16x32_bf16(a, b, c, 0, 0, 0);
}
__device__ inline void gload_lds16(const unsigned short* g, unsigned short* l){
  __builtin_amdgcn_global_load_lds((const __attribute__((address_space(1))) unsigned int*)g,
                                   (__attribute__((address_space(3))) unsigned int*)l, 16, 0, 0);
}
// bijective XCD-chunk swizzle (m204)
__device__ inline int xcd_swizzle(int orig, int nwg){
  int q = nwg >> 3, r = nwg & 7;
  int xcd = orig & 7, off = orig >> 3;
  return (xcd < r ? xcd*(q+1) : r*(q+1) + (xcd-r)*q) + off;
}
__device__ inline float gelu_f(float vv){
  float u = 0.79788456080286535588f*(vv + 0.044715f*vv*vv*vv);
  u = fminf(fmaxf(u, -20.f), 20.f);
  float e2u = __expf(2.f*u);
  float th = (e2u - 1.f)/(e2u + 1.f);
  return 0.5f*vv*(1.f+th);
}

// ---------------- small elementwise kernels ----------------

__global__ void add_vec(const float* __restrict__ a, const float* __restrict__ b,
                        float* __restrict__ o, int n){
  int i = blockIdx.x*256 + threadIdx.x;
  if (i < n) o[i] = a[i] + b[i];
}

__global__ void convert_bf16(const float* __restrict__ a, unsigned short* __restrict__ o, int n){
  int i = blockIdx.x*256 + threadIdx.x;
  if (i < n) o[i] = f2b(a[i]);
}

__global__ void concat3(const float* __restrict__ a, const float* __restrict__ b,
                        const float* __restrict__ c, float* __restrict__ o, int n){
  int i = blockIdx.x*256 + threadIdx.x;
  if (i < n) o[i] = a[i];
  else if (i < 2*n) o[i] = b[i - n];
  else if (i < 3*n) o[i] = c[i - 2*n];
}

// dst[n][k] = bf16(src[k][n]); src is [K][N] row-major. grid (N/32, K/32), block (32,8)
__global__ void transpose_conv(const float* __restrict__ src, unsigned short* __restrict__ dst,
                               int K, int N){
  __shared__ float tile[32][33];
  int n0 = blockIdx.x*32, k0 = blockIdx.y*32;
  int tx = threadIdx.x, ty = threadIdx.y;
  #pragma unroll
  for (int i = 0; i < 4; i++)
    tile[ty + 8*i][tx] = src[(size_t)(k0 + ty + 8*i)*N + n0 + tx];
  __syncthreads();
  #pragma unroll
  for (int i = 0; i < 4; i++)
    dst[(size_t)(n0 + ty + 8*i)*K + k0 + tx] = f2b(tile[tx][ty + 8*i]);
}

// ---------------- layernorm (+adaLN modulation), fp32 in -> bf16 out ----------------
__global__ __launch_bounds__(256) void ln_mod_kernel(const float* __restrict__ x,
    const float* __restrict__ mulv, const float* __restrict__ addv, int one_plus,
    unsigned short* __restrict__ out){
  int row = blockIdx.x;
  const float* xr = x + (size_t)row * DIM;
  int tid = threadIdx.x;
  float v[6]; float s = 0.f, ss = 0.f;
  #pragma unroll
  for (int i = 0; i < 6; i++){ v[i] = xr[tid + i*256]; s += v[i]; ss += v[i]*v[i]; }
  #pragma unroll
  for (int m = 1; m < 64; m <<= 1){ s += __shfl_xor(s, m, 64); ss += __shfl_xor(ss, m, 64); }
  __shared__ float bs[4], bss[4];
  int w = tid >> 6;
  if ((tid & 63) == 0){ bs[w] = s; bss[w] = ss; }
  __syncthreads();
  s = bs[0]+bs[1]+bs[2]+bs[3]; ss = bss[0]+bss[1]+bss[2]+bss[3];
  float mu  = s * (1.f/DIM);
  float var = ss * (1.f/DIM) - mu*mu;
  float inv = rsqrtf(var + 1e-6f);
  unsigned short* orow = out + (size_t)row*DIM;
  #pragma unroll
  for (int i = 0; i < 6; i++){
    int c = tid + i*256;
    float g = one_plus ? (1.f + mulv[c]) : mulv[c];
    orow[c] = f2b((v[i]-mu)*inv*g + addv[c]);
  }
}

// ---------------- fused split-K reduce -> residual update -> LN-mod ----------------
// NOTE: aliasing is intentional at call sites (resid==out_x), no __restrict__.
__global__ __launch_bounds__(256) void reduce_ln_kernel(const float* P0, const float* P1,
    const float* bias, const float* resid, const float* svec, float* out_x,
    const float* mulv, const float* addv, int one_plus, unsigned short* out_ln){
  int row = blockIdx.x;
  size_t base = (size_t)row * DIM;
  int tid = threadIdx.x;
  float v[6]; float s = 0.f, ss = 0.f;
  #pragma unroll
  for (int i = 0; i < 6; i++){
    int c = tid + i*256;
    float sv = svec ? svec[c] : 1.f;
    float y = resid[base + c] + (P0[base + c] + P1[base + c] + bias[c])*sv;
    out_x[base + c] = y;
    v[i] = y; s += y; ss += y*y;
  }
  #pragma unroll
  for (int m = 1; m < 64; m <<= 1){ s += __shfl_xor(s, m, 64); ss += __shfl_xor(ss, m, 64); }
  __shared__ float bs[4], bss[4];
  int w = tid >> 6;
  if ((tid & 63) == 0){ bs[w] = s; bss[w] = ss; }
  __syncthreads();
  s = bs[0]+bs[1]+bs[2]+bs[3]; ss = bss[0]+bss[1]+bss[2]+bss[3];
  float mu  = s * (1.f/DIM);
  float var = ss * (1.f/DIM) - mu*mu;
  float inv = rsqrtf(var + 1e-6f);
  unsigned short* orow = out_ln + base;
  #pragma unroll
  for (int i = 0; i < 6; i++){
    int c = tid + i*256;
    float g = one_plus ? (1.f + mulv[c]) : mulv[c];
    orow[c] = f2b((v[i]-mu)*inv*g + addv[c]);
  }
}

// ---------------- fused split-K reduce -> RMS-norm -> bf16 (ca_q path, no rope) ----------------
__global__ __launch_bounds__(256) void reduce_rms_kernel(const float* __restrict__ P0,
    const float* __restrict__ P1, const float* __restrict__ bias,
    const float* __restrict__ nw, unsigned short* __restrict__ out){
  int row = blockIdx.x;
  size_t base = (size_t)row * DIM;
  int tid = threadIdx.x;
  float v[6]; float ss = 0.f;
  #pragma unroll
  for (int i = 0; i < 6; i++){
    int c = tid + i*256;
    float y = P0[base + c] + P1[base + c] + bias[c];
    v[i] = y; ss += y*y;
  }
  #pragma unroll
  for (int m = 1; m < 64; m <<= 1) ss += __shfl_xor(ss, m, 64);
  __shared__ float bss[4];
  if ((tid & 63) == 0) bss[tid >> 6] = ss;
  __syncthreads();
  ss = bss[0]+bss[1]+bss[2]+bss[3];
  float inv = rsqrtf(ss*(1.f/DIM) + 1e-6f);
  #pragma unroll
  for (int i = 0; i < 6; i++){
    int c = tid + i*256;
    out[base + c] = f2b(v[i]*inv*nw[c]);
  }
}

// ---------------- fused RMS+RoPE for Q and K slices of qkv16, one launch ----------------
__global__ __launch_bounds__(256) void rms_rope_qk(unsigned short* __restrict__ buf,
    const float* __restrict__ nwq, const float* __restrict__ nwk,
    const float* __restrict__ ct, const float* __restrict__ st){
  int row = blockIdx.x;
  int sl = blockIdx.y;
  const float* nw = sl ? nwk : nwq;
  unsigned short* xr = buf + (size_t)row*(3*DIM) + sl*DIM;
  int tid = threadIdx.x;
  float ss = 0.f; float v[6];
  #pragma unroll
  for (int i = 0; i < 6; i++){ v[i] = b2f(xr[tid + i*256]); ss += v[i]*v[i]; }
  #pragma unroll
  for (int m = 1; m < 64; m <<= 1) ss += __shfl_xor(ss, m, 64);
  __shared__ float bss[4];
  if ((tid & 63) == 0) bss[tid >> 6] = ss;
  __syncthreads();
  ss = bss[0]+bss[1]+bss[2]+bss[3];
  float inv = rsqrtf(ss*(1.f/DIM) + 1e-6f);
  int f = row/400, hp = (row/20)%20, wp = row%20;   // Fg=8, Hg=20, Wg=20
  for (int p = tid; p < 768; p += 256){
    int hh = p >> 6, j = p & 63;                     // head, freq index (c=64)
    int pos = (j < 22) ? f : ((j < 43) ? hp : wp);   // c0=22, c1=21
    float c_ = ct[pos*64 + j], s_ = st[pos*64 + j];
    int base = hh*HD + 2*j;
    float xre = b2f(xr[base])   * inv * nw[base];
    float xim = b2f(xr[base+1]) * inv * nw[base+1];
    xr[base]   = f2b(xre*c_ - xim*s_);
    xr[base+1] = f2b(xre*s_ + xim*c_);
  }
}

// ---------------- RMS norm (no rope), bf16 IN-PLACE, row stride ld ----------------
__global__ __launch_bounds__(256) void rms_rope_b16(unsigned short* __restrict__ buf, int ld,
    const float* __restrict__ nw){
  int row = blockIdx.x;
  unsigned short* xr = buf + (size_t)row*ld;
  int tid = threadIdx.x;
  float ss = 0.f; float v[6];
  #pragma unroll
  for (int i = 0; i < 6; i++){ v[i] = b2f(xr[tid + i*256]); ss += v[i]*v[i]; }
  #pragma unroll
  for (int m = 1; m < 64; m <<= 1) ss += __shfl_xor(ss, m, 64);
  __shared__ float bss[4];
  if ((tid & 63) == 0) bss[tid >> 6] = ss;
  __syncthreads();
  ss = bss[0]+bss[1]+bss[2]+bss[3];
  float inv = rsqrtf(ss*(1.f/DIM) + 1e-6f);
  #pragma unroll
  for (int i = 0; i < 6; i++){ int c = tid + i*256; xr[c] = f2b(v[i]*inv*nw[c]); }
}

// ---------------- pack V transposed per head: VT[h][d][tok]; bf16 in, row stride ld ----------------
__global__ __launch_bounds__(256) void packvt_kernel(const unsigned short* __restrict__ pre, int ld,
    unsigned short* __restrict__ VT, int ntok){
  int h = blockIdx.y; int t0 = blockIdx.x*64;
  __shared__ unsigned short tile[128][72];
  int tid = threadIdx.x;
  int d = tid & 127, tl = tid >> 7;
  #pragma unroll 4
  for (int i = 0; i < 32; i++){
    int tok = t0 + tl + 2*i;
    tile[d][tl + 2*i] = pre[(size_t)tok*ld + h*HD + d];
  }
  __syncthreads();
  int dd = tid >> 6, tl2 = tid & 63;
  #pragma unroll 4
  for (int i = 0; i < 32; i++){
    int d2 = dd + 4*i;
    VT[((size_t)h*HD + d2)*ntok + t0 + tl2] = tile[d2][tl2];
  }
}

// ---------------- split-K reduce epilogue, 2 or 3 partials (P2 may be null) ----------------
__global__ void reduce_f32(const float* P0, const float* P1, const float* P2,
    const float* bias, const float* resid,
    const float* svec, float* out, int total4){
  int i = blockIdx.x*256 + threadIdx.x;
  if (i >= total4) return;
  int col = (i*4) % DIM;
  float4 p0 = ((const float4*)P0)[i];
  float4 p1 = ((const float4*)P1)[i];
  float4 p2 = P2 ? ((const float4*)P2)[i] : make_float4(0.f,0.f,0.f,0.f);
  float4 rs = ((const float4*)resid)[i];
  float4 o;
  float s0 = svec ? svec[col]   : 1.f;
  float s1 = svec ? svec[col+1] : 1.f;
  float s2 = svec ? svec[col+2] : 1.f;
  float s3 = svec ? svec[col+3] : 1.f;
  o.x = rs.x + (p0.x + p1.x + p2.x + bias[col])*s0;
  o.y = rs.y + (p0.y + p1.y + p2.y + bias[col+1])*s1;
  o.z = rs.z + (p0.z + p1.z + p2.z + bias[col+2])*s2;
  o.w = rs.w + (p0.w + p1.w + p2.w + bias[col+3])*s3;
  ((float4*)out)[i] = o;
}

// ---------------- 128x128 GEMM, 512 threads / 8 waves (4m x 2n), BK=32 (r12 proven) ----------------
// kbeg = z*ksize, slice length = min(ksize, Ktot-kbeg). ep4 -> fp32 partial into o[z].
__global__ __launch_bounds__(512, 4) void gemm128_kernel(const unsigned short* __restrict__ A,
    const unsigned short* __restrict__ WT, const float* __restrict__ bias,
    int M, int N, int ldA, int Ktot, int ksize, int ep,
    float* o0, float* o1, float* o2, unsigned short* __restrict__ outb){
  __shared__ unsigned short As[2][128*32];
  __shared__ unsigned short Bs[2][128*32];
  int t = threadIdx.x;
  int wv = t >> 6, lane = t & 63;
  int lr = lane & 15, lk = lane >> 4;
  int gx = gridDim.x;
  int nwg = gx * gridDim.y;
  int wg = xcd_swizzle(blockIdx.y*gx + blockIdx.x, nwg);
  int m0 = (wg % gx)*128, n0 = (wg / gx)*128;
  int kbeg = blockIdx.z*ksize;
  int keff = Ktot - kbeg; if (keff > ksize) keff = ksize;
  int wm = (wv >> 1)*32, wn = (wv & 1)*64;   // 4 m-waves x 2 n-waves; 32x64 per wave
  f32x4 z = {0.f,0.f,0.f,0.f};
  f32x4 acc[2][4];
  #pragma unroll
  for (int i = 0; i < 2; i++)
    #pragma unroll
    for (int j = 0; j < 4; j++) acc[i][j] = z;

  int srow = t >> 2;
  int sslot = (t & 3) ^ (srow & 3);
  const unsigned short* Ap0 = A  + (size_t)(m0 + srow)*ldA + kbeg + sslot*8;
  const unsigned short* Bp0 = WT + (size_t)(n0 + srow)*ldA + kbeg + sslot*8;
  int slA = (lk ^ (lr & 3))*8;

  int nk = keff >> 5;
  gload_lds16(Ap0, &As[0][wv*512]);
  gload_lds16(Bp0, &Bs[0][wv*512]);
  asm volatile("s_waitcnt vmcnt(0)" ::: "memory");
  __syncthreads();

  for (int tt = 0; tt < nk; ++tt){
    int cur = tt & 1;
    if (tt + 1 < nk){
      int kn = (tt + 1) << 5;
      gload_lds16(Ap0 + kn, &As[cur^1][wv*512]);
      gload_lds16(Bp0 + kn, &Bs[cur^1][wv*512]);
    }
    bf16x8 af[2], bfr[4];
    #pragma unroll
    for (int i = 0; i < 2; i++)
      af[i]  = *(const bf16x8*)&As[cur][(wm + i*16 + lr)*32 + slA];
    #pragma unroll
    for (int j = 0; j < 4; j++)
      bfr[j] = *(const bf16x8*)&Bs[cur][(wn + j*16 + lr)*32 + slA];
    #pragma unroll
    for (int i = 0; i < 2; i++)
      #pragma unroll
      for (int j = 0; j < 4; j++)
        acc[i][j] = mfma16(af[i], bfr[j], acc[i][j]);
    asm volatile("s_waitcnt vmcnt(0)" ::: "memory");
    __syncthreads();
  }

  float* pdst = (blockIdx.z == 0) ? o0 : (blockIdx.z == 1) ? o1 : o2;
  #pragma unroll
  for (int i = 0; i < 2; i++)
    #pragma unroll
    for (int j = 0; j < 4; j++)
      #pragma unroll
      for (int r = 0; r < 4; r++){
        int row = m0 + wm + i*16 + lk*4 + r;
        int col = n0 + wn + j*16 + lr;
        size_t idx = (size_t)row*N + col;
        if (ep == 4){
          pdst[idx] = acc[i][j][r];
        } else if (ep == 3){
          outb[idx] = f2b(acc[i][j][r] + bias[col]);
        } else {
          outb[idx] = f2b(gelu_f(acc[i][j][r] + bias[col]));
        }
      }
}

// ---------------- 128x256 GEMM, 512 threads / 8 waves (2m x 4n, 64x64 each), BK=32 ----------------
__global__ __launch_bounds__(512, 4) void gemmw_kernel(const unsigned short* __restrict__ A,
    const unsigned short* __restrict__ WT, const float* __restrict__ bias,
    int M, int N, int ldA, int K, int ep, unsigned short* __restrict__ outb){
  __shared__ unsigned short As[2][128*32];
  __shared__ unsigned short Bs[2][256*32];
  int t = threadIdx.x;
  int wv = t >> 6, lane = t & 63;
  int lr = lane & 15, lk = lane >> 4;
  int gx = gridDim.x;
  int wg = xcd_swizzle(blockIdx.y*gx + blockIdx.x, gx*gridDim.y);
  int m0 = (wg % gx)*128, n0 = (wg / gx)*256;
  int wm = (wv >> 2)*64, wn = (wv & 3)*64;   // 2 m-waves x 4 n-waves; 64x64 per wave
  f32x4 z = {0.f,0.f,0.f,0.f};
  f32x4 acc[4][4];
  #pragma unroll
  for (int i = 0; i < 4; i++)
    #pragma unroll
    for (int j = 0; j < 4; j++) acc[i][j] = z;

  int srow = t >> 2;                         // 0..127
  int sslot = (t & 3) ^ (srow & 3);
  const unsigned short* Ap0 = A  + (size_t)(m0 + srow)*ldA + sslot*8;
  const unsigned short* Bp0 = WT + (size_t)(n0 + srow)*ldA + sslot*8;
  const unsigned short* Bp1 = WT + (size_t)(n0 + 128 + srow)*ldA + sslot*8;
  int slA = (lk ^ (lr & 3))*8;

  int nk = K >> 5;
  gload_lds16(Ap0, &As[0][wv*512]);
  gload_lds16(Bp0, &Bs[0][wv*512]);
  gload_lds16(Bp1, &Bs[0][4096 + wv*512]);
  asm volatile("s_waitcnt vmcnt(0)" ::: "memory");
  __syncthreads();

  for (int tt = 0; tt < nk; ++tt){
    int cur = tt & 1;
    if (tt + 1 < nk){
      int kn = (tt + 1) << 5;
      gload_lds16(Ap0 + kn, &As[cur^1][wv*512]);
      gload_lds16(Bp0 + kn, &Bs[cur^1][wv*512]);
      gload_lds16(Bp1 + kn, &Bs[cur^1][4096 + wv*512]);
    }
    bf16x8 af[4], bfr[4];
    #pragma unroll
    for (int i = 0; i < 4; i++)
      af[i]  = *(const bf16x8*)&As[cur][(wm + i*16 + lr)*32 + slA];
    #pragma unroll
    for (int j = 0; j < 4; j++)
      bfr[j] = *(const bf16x8*)&Bs[cur][(wn + j*16 + lr)*32 + slA];
    #pragma unroll
    for (int i = 0; i < 4; i++)
      #pragma unroll
      for (int j = 0; j < 4; j++)
        acc[i][j] = mfma16(af[i], bfr[j], acc[i][j]);
    asm volatile("s_waitcnt vmcnt(0)" ::: "memory");
    __syncthreads();
  }

  #pragma unroll
  for (int i = 0; i < 4; i++)
    #pragma unroll
    for (int j = 0; j < 4; j++)
      #pragma unroll
      for (int r = 0; r < 4; r++){
        int row = m0 + wm + i*16 + lk*4 + r;
        int col = n0 + wn + j*16 + lr;
        size_t idx = (size_t)row*N + col;
        float vv = acc[i][j][r] + bias[col];
        outb[idx] = (ep == 3) ? f2b(vv) : f2b(gelu_f(vv));
      }
}

// ---------------- flash attention, swapped-QK, KV-SPLIT via blockIdx.z ----------------
__global__ __launch_bounds__(256, 3) void attn_kernel(const unsigned short* __restrict__ Q, int ldQ,
    const unsigned short* __restrict__ Kg, int ldK, const unsigned short* __restrict__ VT,
    unsigned short* O, int nkv, int vlen, int kvchunk,
    float2* ml, unsigned short* op0, unsigned short* op1){
  __shared__ unsigned short Kls[64*128];
  __shared__ unsigned short Vls[128*64];
  __shared__ unsigned short Pls[4][16][80];
  int gx = gridDim.x;
  int wg = xcd_swizzle(blockIdx.y*gx + blockIdx.x, gx*gridDim.y);
  int bq = wg % gx, h = wg / gx;
  int zi = blockIdx.z;
  int kv0 = zi*kvchunk;
  int tid = threadIdx.x;
  int wv = tid >> 6, lane = tid & 63;
  int lr = lane & 15, lk = lane >> 4;
  int q0 = bq*64 + wv*16;

  bf16x8 qf[4];
  const unsigned short* qp = Q + (size_t)(q0 + lr)*ldQ + h*HD + lk*8;
  #pragma unroll
  for (int kk = 0; kk < 4; kk++) qf[kk] = *(const bf16x8*)(qp + kk*32);

  f32x4 z = {0.f,0.f,0.f,0.f};
  f32x4 acc[8];
  #pragma unroll
  for (int d = 0; d < 8; d++) acc[d] = z;
  float mrun = -1e30f, lrun = 0.f;
  const float sc = 0.08838834764831845f;
  int swz = (lr & 7) << 4;

  for (int kt = kv0; kt < kv0 + kvchunk; kt += 64){
    __syncthreads();
    #pragma unroll
    for (int j = 0; j < 4; j++){
      int row = wv*16 + j*4 + (lane >> 4);
      int cb  = ((lane & 15)*16) ^ ((row & 7) << 4);
      gload_lds16(Kg + (size_t)(kt + row)*ldK + h*HD + (cb >> 1),
                  &Kls[(wv*16 + j*4)*128]);
    }
    #pragma unroll
    for (int j = 0; j < 4; j++){
      int d  = wv*32 + j*8 + (lane >> 3);
      int cb = ((lane & 7)*16) ^ ((d & 7) << 4);
      gload_lds16(VT + ((size_t)h*HD + d)*vlen + kt + (cb >> 1),
                  &Vls[(wv*32 + j*8)*64]);
    }
    asm volatile("s_waitcnt vmcnt(0)" ::: "memory");
    __syncthreads();

    f32x4 s[4];
    #pragma unroll
    for (int t4 = 0; t4 < 4; t4++) s[t4] = z;
    #pragma unroll
    for (int t4 = 0; t4 < 4; t4++){
      #pragma unroll
      for (int kk = 0; kk < 4; kk++){
        bf16x8 kf = *(const bf16x8*)&Kls[(t4*16 + lr)*128 + (((kk*64 + lk*16) ^ swz) >> 1)];
        s[t4] = mfma16(kf, qf[kk], s[t4]);
      }
    }

    float vv[4][4]; float pmax = -1e30f;
    #pragma unroll
    for (int t4 = 0; t4 < 4; t4++)
      #pragma unroll
      for (int r = 0; r < 4; r++){
        float xv = s[t4][r]*sc; vv[t4][r] = xv; pmax = fmaxf(pmax, xv);
      }
    pmax = fmaxf(pmax, __shfl_xor(pmax, 16, 64));
    pmax = fmaxf(pmax, __shfl_xor(pmax, 32, 64));

    if (__all(pmax - mrun <= 8.f)){
      float rs = 0.f;
      #pragma unroll
      for (int t4 = 0; t4 < 4; t4++)
        #pragma unroll
        for (int r = 0; r < 4; r++){
          float pv = __expf(vv[t4][r] - mrun); vv[t4][r] = pv; rs += pv;
        }
      rs += __shfl_xor(rs, 16, 64);
      rs += __shfl_xor(rs, 32, 64);
      lrun += rs;
    } else {
      float mn = fmaxf(mrun, pmax);
      float cr = __expf(mrun - mn);
      mrun = mn;
      float rs = 0.f;
      #pragma unroll
      for (int t4 = 0; t4 < 4; t4++)
        #pragma unroll
        for (int r = 0; r < 4; r++){
          float pv = __expf(vv[t4][r] - mn); vv[t4][r] = pv; rs += pv;
        }
      rs += __shfl_xor(rs, 16, 64);
      rs += __shfl_xor(rs, 32, 64);
      lrun = lrun*cr + rs;
      #pragma unroll
      for (int d = 0; d < 8; d++) acc[d] *= cr;
    }

    #pragma unroll
    for (int t4 = 0; t4 < 4; t4++){
      *(unsigned*)&Pls[wv][lr][t4*16 + lk*4]     = pack2(vv[t4][0], vv[t4][1]);
      *(unsigned*)&Pls[wv][lr][t4*16 + lk*4 + 2] = pack2(vv[t4][2], vv[t4][3]);
    }
    bf16x8 pb0 = *(const bf16x8*)&Pls[wv][lr][lk*8];
    bf16x8 pb1 = *(const bf16x8*)&Pls[wv][lr][32 + lk*8];

    #pragma unroll
    for (int db = 0; db < 8; db++){
      bf16x8 vf0 = *(const bf16x8*)&Vls[(db*16 + lr)*64 + (((lk*16) ^ swz) >> 1)];
      acc[db] = mfma16(vf0, pb0, acc[db]);
      bf16x8 vf1 = *(const bf16x8*)&Vls[(db*16 + lr)*64 + (((64 + lk*16) ^ swz) >> 1)];
      acc[db] = mfma16(vf1, pb1, acc[db]);
    }
  }

  float inv = 1.f/lrun;
  unsigned short* od = (gridDim.z == 1) ? O : (zi ? op1 : op0);
  unsigned short* op = od + (size_t)(q0 + lr)*DIM + h*HD + lk*4;
  #pragma unroll
  for (int db = 0; db < 8; db++){
    u16x4 ov;
    ov[0] = f2b(acc[db][0]*inv); ov[1] = f2b(acc[db][1]*inv);
    ov[2] = f2b(acc[db][2]*inv); ov[3] = f2b(acc[db][3]*inv);
    *(u16x4*)(op + db*16) = ov;
  }
  if (gridDim.z > 1 && lk == 0)
    ml[((size_t)zi*NH + h)*LQ + (q0 + lr)] = make_float2(mrun, lrun);
}

// ---------------- combine 2 KV-split partials: O = a0*O0 + a1*O1 per head ----------------
__global__ __launch_bounds__(256) void attn_combine(const unsigned short* __restrict__ op0,
    const unsigned short* __restrict__ op1, const float2* __restrict__ ml,
    unsigned short* __restrict__ O){
  int row = blockIdx.x;
  int tid = threadIdx.x;
  __shared__ float w0s[NH], w1s[NH];
  if (tid < NH){
    float2 a = ml[(size_t)tid*LQ + row];
    float2 b = ml[((size_t)NH + tid)*LQ + row];
    float ms = fmaxf(a.x, b.x);
    float e0 = __expf(a.x - ms)*a.y;
    float e1 = __expf(b.x - ms)*b.y;
    float inv = 1.f/(e0 + e1);
    w0s[tid] = e0*inv; w1s[tid] = e1*inv;
  }
  __syncthreads();
  size_t base = (size_t)row*DIM;
  #pragma unroll
  for (int i = 0; i < 2; i++){
    int c4 = tid + i*256;
    if (c4 < 384){
      int h = c4 >> 5;                       // (c4*4)/128
      u16x4 a = *(const u16x4*)(op0 + base + c4*4);
      u16x4 b = *(const u16x4*)(op1 + base + c4*4);
      u16x4 o;
      #pragma unroll
      for (int j = 0; j < 4; j++)
        o[j] = f2b(b2f(a[j])*w0s[h] + b2f(b[j])*w1s[h]);
      *(u16x4*)(O + base + c4*4) = o;
    }
  }
}

// ---------------- host launch ----------------

extern "C" void kernel_launch(void* const* d_in, const int* in_sizes, int n_in,
                              void* d_out, int out_size, void* d_ws, size_t ws_size,
                              hipStream_t stream){
  const float* x    = (const float*)d_in[0];
  const float* e    = (const float*)d_in[1];
  const float* ctx  = (const float*)d_in[2];
  const float* fcos = (const float*)d_in[3];
  const float* fsin = (const float*)d_in[4];
  const float* modu = (const float*)d_in[5];
  const float* sa_qw = (const float*)d_in[6];  const float* sa_qb = (const float*)d_in[7];
  const float* sa_kw = (const float*)d_in[8];  const float* sa_kb = (const float*)d_in[9];
  const float* sa_vw = (const float*)d_in[10]; const float* sa_vb = (const float*)d_in[11];
  const float* sa_ow = (const float*)d_in[12]; const float* sa_ob = (const float*)d_in[13];
  const float* sa_nq = (const float*)d_in[14]; const float* sa_nk = (const float*)d_in[15];
  const float* ca_qw = (const float*)d_in[16]; const float* ca_qb = (const float*)d_in[17];
  const float* ca_kw = (const float*)d_in[18]; const float* ca_kb = (const float*)d_in[19];
  const float* ca_vw = (const float*)d_in[20]; const float* ca_vb = (const float*)d_in[21];
  const float* ca_ow = (const float*)d_in[22]; const float* ca_ob = (const float*)d_in[23];
  const float* ca_nq = (const float*)d_in[24]; const float* ca_nk = (const float*)d_in[25];
  const float* n3w = (const float*)d_in[26]; const float* n3b = (const float*)d_in[27];
  const float* fw1 = (const float*)d_in[28]; const float* fb1 = (const float*)d_in[29];
  const float* fw2 = (const float*)d_in[30]; const float* fb2 = (const float*)d_in[31];

  char* p = (char*)d_ws;
  auto alloc = [&](size_t bytes){ void* r = (void*)p; p += (bytes + 255) & ~(size_t)255; return r; };
  unsigned short* wt[8];
  for (int i = 0; i < 8; i++) wt[i] = (unsigned short*)alloc((size_t)DIM*DIM*2);
  unsigned short* wtf1 = (unsigned short*)alloc((size_t)FFN*DIM*2);   // dead after FFN1
  unsigned short* wtf2 = (unsigned short*)alloc((size_t)DIM*FFN*2);
  float* em     = (float*)alloc(6*DIM*4);
  float* qkvb   = (float*)alloc(3*DIM*4);
  float* ckvb   = (float*)alloc(2*DIM*4);
  float2* mlb   = (float2*)alloc((size_t)2*NH*LQ*sizeof(float2));
  unsigned short* nbuf = (unsigned short*)alloc((size_t)LQ*DIM*2);
  // dead-chain for FFN overlay: qkv16+VTb+Qb+Ob = 59.0M >= 57.3M
  unsigned short* qkv16 = (unsigned short*)alloc((size_t)LQ*3*DIM*2);   // [3200][4608]
  unsigned short* VTb   = (unsigned short*)alloc((size_t)LQ*DIM*2);
  unsigned short* Qb    = (unsigned short*)alloc((size_t)LQ*DIM*2);
  unsigned short* Ob    = (unsigned short*)alloc((size_t)LQ*DIM*2);
  float* x1 = (float*)alloc((size_t)LQ*DIM*4);
  unsigned short* ctxb   = (unsigned short*)alloc((size_t)LKV*DIM*2);
  unsigned short* cakv16 = (unsigned short*)alloc((size_t)LKV*2*DIM*2); // [512][3072]
  float* P2x = (float*)alloc((size_t)LQ*DIM*4);   // third FFN2 partial (dedicated, 19.7MB)

  float* P0   = (float*)d_out;        // scratch until its branch's reduce
  float* P1a  = (float*)qkv16;        // 19.66M partial (qkv16 dead at use sites)
  float* P1f  = (float*)wtf1;         // FFN2 partial (wtf1 dead after FFN1)
  unsigned short* hbuf = qkv16;       // FFN hidden [3200][8960] over dead chain
  // self-attn KV-split partials: Qb (z=0) and x1 bytes (z=1) — both dead until combine
  unsigned short* opz0 = Qb;
  unsigned short* opz1 = (unsigned short*)x1;
  const int TOT4 = LQ*DIM/4;

  // prep
  add_vec<<<36, 256, 0, stream>>>(modu, e, em, 6*DIM);
  concat3<<<18, 256, 0, stream>>>(sa_qb, sa_kb, sa_vb, qkvb, DIM);
  concat3<<<12, 256, 0, stream>>>(ca_kb, ca_vb, ca_vb, ckvb, DIM);
  const float* wsrc[8] = {sa_qw, sa_kw, sa_vw, sa_ow, ca_qw, ca_kw, ca_vw, ca_ow};
  for (int i = 0; i < 8; i++)
    transpose_conv<<<dim3(48,48), dim3(32,8), 0, stream>>>(wsrc[i], wt[i], DIM, DIM);
  transpose_conv<<<dim3(280,48), dim3(32,8), 0, stream>>>(fw1, wtf1, DIM, FFN);
  transpose_conv<<<dim3(48,280), dim3(32,8), 0, stream>>>(fw2, wtf2, FFN, DIM);
  convert_bf16<<<(LKV*DIM)/256, 256, 0, stream>>>(ctx, ctxb, LKV*DIM);

  // ---- self-attention branch ----
  ln_mod_kernel<<<LQ, 256, 0, stream>>>(x, em + DIM, em, 1, nbuf);
  gemmw_kernel<<<dim3(25,18), 512, 0, stream>>>(nbuf, wt[0], qkvb, LQ, 3*DIM, DIM, DIM, 3, qkv16);
  rms_rope_qk<<<dim3(LQ,2), 256, 0, stream>>>(qkv16, sa_nq, sa_nk, fcos, fsin);
  packvt_kernel<<<dim3(50,12), 256, 0, stream>>>(qkv16 + 2*DIM, 3*DIM, VTb, LQ);
  attn_kernel<<<dim3(50,12,2), 256, 0, stream>>>(qkv16, 3*DIM, qkv16 + DIM, 3*DIM, VTb,
                                                 nullptr, LQ, LQ, LQ/2, mlb, opz0, opz1);
  attn_combine<<<LQ, 256, 0, stream>>>(opz0, opz1, mlb, Ob);
  gemm128_kernel<<<dim3(25,12,2), 512, 0, stream>>>(Ob, wt[3], nullptr, LQ, DIM, DIM, DIM, DIM/2, 4,
                                                    P0, P1a, nullptr, nullptr);
  reduce_ln_kernel<<<LQ, 256, 0, stream>>>(P0, P1a, sa_ob, x, em + 2*DIM, x1,
                                           n3w, n3b, 0, nbuf);

  // ---- cross-attention branch ----
  gemm128_kernel<<<dim3(25,12,2), 512, 0, stream>>>(nbuf, wt[4], nullptr, LQ, DIM, DIM, DIM, DIM/2, 4,
                                                    P0, P1a, nullptr, nullptr);
  reduce_rms_kernel<<<LQ, 256, 0, stream>>>(P0, P1a, ca_qb, ca_nq, Qb);
  gemm128_kernel<<<dim3(4,24,1), 512, 0, stream>>>(ctxb, wt[5], ckvb, LKV, 2*DIM, DIM, DIM, DIM, 3,
                                                   nullptr, nullptr, nullptr, cakv16);
  rms_rope_b16<<<LKV, 256, 0, stream>>>(cakv16, 2*DIM, ca_nk);
  packvt_kernel<<<dim3(8,12), 256, 0, stream>>>(cakv16 + DIM, 2*DIM, VTb, LKV);
  attn_kernel<<<dim3(50,12,1), 256, 0, stream>>>(Qb, DIM, cakv16, 2*DIM, VTb,
                                                 Ob, LKV, LKV, LKV, nullptr, nullptr, nullptr);
  gemm128_kernel<<<dim3(25,12,2), 512, 0, stream>>>(Ob, wt[7], nullptr, LQ, DIM, DIM, DIM, DIM/2, 4,
                                                    P0, P1a, nullptr, nullptr);
  reduce_ln_kernel<<<LQ, 256, 0, stream>>>(P0, P1a, ca_ob, x1, nullptr, x1,
                                           em + 4*DIM, em + 3*DIM, 1, nbuf);

  // ---- FFN branch ----
  gemmw_kernel<<<dim3(25,35), 512, 0, stream>>>(nbuf, wtf1, fb1, LQ, FFN, DIM, DIM, 2, hbuf);
  // FFN2 split-K x3: slices 3008/3008/2944 (94/94/92 K-steps), 900 blocks
  gemm128_kernel<<<dim3(25,12,3), 512, 0, stream>>>(hbuf, wtf2, nullptr, LQ, DIM, FFN, FFN, 3008, 4,
                                                    P0, P1f, P2x, nullptr);
  reduce_f32<<<(TOT4+255)/256, 256, 0, stream>>>(P0, P1f, P2x, fb2, x1, em + 5*DIM,
                                                 (float*)d_out, TOT4);
}

// Round 18
// 749.398 us; speedup vs baseline: 1.0372x; 1.0372x over previous
//
#include <hip/hip_runtime.h>

#define DIM 1536
#define NH 12
#define HD 128
#define LQ 3200
#define LKV 512
#define FFN 8960

typedef __attribute__((ext_vector_type(8))) short bf16x8;
typedef __attribute__((ext_vector_type(4))) float f32x4;
typedef __attribute__((ext_vector_type(4))) unsigned short u16x4;

__device__ inline unsigned short f2b(float f){
  union { float f; unsigned u; } x; x.f = f;
  unsigned r = (x.u + 0x7FFFu + ((x.u >> 16) & 1u)) >> 16;
  return (unsigned short)r;
}
__device__ inline float b2f(unsigned short u){
  union { unsigned u; float f; } x; x.u = ((unsigned)u) << 16; return x.f;
}
__device__ inline unsigned pack2(float a, float b){
  return (unsigned)f2b(a) | ((unsigned)f2b(b) << 16);
}
__device__ inline f32x4 mfma16(bf16x8 a, bf16x8 b, f32x4 c){
  return __builtin_amdgcn_mfma_f32_16x16x32_bf16(a, b, c, 0, 0, 0);
}
__device__ inline void gload_lds16(const unsigned short* g, unsigned short* l){
  __builtin_amdgcn_global_load_lds((const __attribute__((address_space(1))) unsigned int*)g,
                                   (__attribute__((address_space(3))) unsigned int*)l, 16, 0, 0);
}
// bijective XCD-chunk swizzle (m204)
__device__ inline int xcd_swizzle(int orig, int nwg){
  int q = nwg >> 3, r = nwg & 7;
  int xcd = orig & 7, off = orig >> 3;
  return (xcd < r ? xcd*(q+1) : r*(q+1) + (xcd-r)*q) + off;
}
__device__ inline float gelu_f(float vv){
  float u = 0.79788456080286535588f*(vv + 0.044715f*vv*vv*vv);
  u = fminf(fmaxf(u, -20.f), 20.f);
  float e2u = __expf(2.f*u);
  float th = (e2u - 1.f)/(e2u + 1.f);
  return 0.5f*vv*(1.f+th);
}

// ---------------- small elementwise kernels ----------------

__global__ void add_vec(const float* __restrict__ a, const float* __restrict__ b,
                        float* __restrict__ o, int n){
  int i = blockIdx.x*256 + threadIdx.x;
  if (i < n) o[i] = a[i] + b[i];
}

__global__ void convert_bf16(const float* __restrict__ a, unsigned short* __restrict__ o, int n){
  int i = blockIdx.x*256 + threadIdx.x;
  if (i < n) o[i] = f2b(a[i]);
}

__global__ void concat3(const float* __restrict__ a, const float* __restrict__ b,
                        const float* __restrict__ c, float* __restrict__ o, int n){
  int i = blockIdx.x*256 + threadIdx.x;
  if (i < n) o[i] = a[i];
  else if (i < 2*n) o[i] = b[i - n];
  else if (i < 3*n) o[i] = c[i - 2*n];
}

// dst[n][k] = bf16(src[k][n]); src is [K][N] row-major. grid (N/32, K/32), block (32,8)
__global__ void transpose_conv(const float* __restrict__ src, unsigned short* __restrict__ dst,
                               int K, int N){
  __shared__ float tile[32][33];
  int n0 = blockIdx.x*32, k0 = blockIdx.y*32;
  int tx = threadIdx.x, ty = threadIdx.y;
  #pragma unroll
  for (int i = 0; i < 4; i++)
    tile[ty + 8*i][tx] = src[(size_t)(k0 + ty + 8*i)*N + n0 + tx];
  __syncthreads();
  #pragma unroll
  for (int i = 0; i < 4; i++)
    dst[(size_t)(n0 + ty + 8*i)*K + k0 + tx] = f2b(tile[tx][ty + 8*i]);
}

// ---------------- layernorm (+adaLN modulation), fp32 in -> bf16 out ----------------
__global__ __launch_bounds__(256) void ln_mod_kernel(const float* __restrict__ x,
    const float* __restrict__ mulv, const float* __restrict__ addv, int one_plus,
    unsigned short* __restrict__ out){
  int row = blockIdx.x;
  const float* xr = x + (size_t)row * DIM;
  int tid = threadIdx.x;
  float v[6]; float s = 0.f, ss = 0.f;
  #pragma unroll
  for (int i = 0; i < 6; i++){ v[i] = xr[tid + i*256]; s += v[i]; ss += v[i]*v[i]; }
  #pragma unroll
  for (int m = 1; m < 64; m <<= 1){ s += __shfl_xor(s, m, 64); ss += __shfl_xor(ss, m, 64); }
  __shared__ float bs[4], bss[4];
  int w = tid >> 6;
  if ((tid & 63) == 0){ bs[w] = s; bss[w] = ss; }
  __syncthreads();
  s = bs[0]+bs[1]+bs[2]+bs[3]; ss = bss[0]+bss[1]+bss[2]+bss[3];
  float mu  = s * (1.f/DIM);
  float var = ss * (1.f/DIM) - mu*mu;
  float inv = rsqrtf(var + 1e-6f);
  unsigned short* orow = out + (size_t)row*DIM;
  #pragma unroll
  for (int i = 0; i < 6; i++){
    int c = tid + i*256;
    float g = one_plus ? (1.f + mulv[c]) : mulv[c];
    orow[c] = f2b((v[i]-mu)*inv*g + addv[c]);
  }
}

// ---------------- fused split-K reduce -> residual update -> LN-mod ----------------
// NOTE: aliasing is intentional at call sites (resid==out_x), no __restrict__.
__global__ __launch_bounds__(256) void reduce_ln_kernel(const float* P0, const float* P1,
    const float* bias, const float* resid, const float* svec, float* out_x,
    const float* mulv, const float* addv, int one_plus, unsigned short* out_ln){
  int row = blockIdx.x;
  size_t base = (size_t)row * DIM;
  int tid = threadIdx.x;
  float v[6]; float s = 0.f, ss = 0.f;
  #pragma unroll
  for (int i = 0; i < 6; i++){
    int c = tid + i*256;
    float sv = svec ? svec[c] : 1.f;
    float y = resid[base + c] + (P0[base + c] + P1[base + c] + bias[c])*sv;
    out_x[base + c] = y;
    v[i] = y; s += y; ss += y*y;
  }
  #pragma unroll
  for (int m = 1; m < 64; m <<= 1){ s += __shfl_xor(s, m, 64); ss += __shfl_xor(ss, m, 64); }
  __shared__ float bs[4], bss[4];
  int w = tid >> 6;
  if ((tid & 63) == 0){ bs[w] = s; bss[w] = ss; }
  __syncthreads();
  s = bs[0]+bs[1]+bs[2]+bs[3]; ss = bss[0]+bss[1]+bss[2]+bss[3];
  float mu  = s * (1.f/DIM);
  float var = ss * (1.f/DIM) - mu*mu;
  float inv = rsqrtf(var + 1e-6f);
  unsigned short* orow = out_ln + base;
  #pragma unroll
  for (int i = 0; i < 6; i++){
    int c = tid + i*256;
    float g = one_plus ? (1.f + mulv[c]) : mulv[c];
    orow[c] = f2b((v[i]-mu)*inv*g + addv[c]);
  }
}

// ---------------- fused split-K reduce -> RMS-norm -> bf16 (ca_q path, no rope) ----------------
__global__ __launch_bounds__(256) void reduce_rms_kernel(const float* __restrict__ P0,
    const float* __restrict__ P1, const float* __restrict__ bias,
    const float* __restrict__ nw, unsigned short* __restrict__ out){
  int row = blockIdx.x;
  size_t base = (size_t)row * DIM;
  int tid = threadIdx.x;
  float v[6]; float ss = 0.f;
  #pragma unroll
  for (int i = 0; i < 6; i++){
    int c = tid + i*256;
    float y = P0[base + c] + P1[base + c] + bias[c];
    v[i] = y; ss += y*y;
  }
  #pragma unroll
  for (int m = 1; m < 64; m <<= 1) ss += __shfl_xor(ss, m, 64);
  __shared__ float bss[4];
  if ((tid & 63) == 0) bss[tid >> 6] = ss;
  __syncthreads();
  ss = bss[0]+bss[1]+bss[2]+bss[3];
  float inv = rsqrtf(ss*(1.f/DIM) + 1e-6f);
  #pragma unroll
  for (int i = 0; i < 6; i++){
    int c = tid + i*256;
    out[base + c] = f2b(v[i]*inv*nw[c]);
  }
}

// ---------------- fused RMS+RoPE for Q and K slices of qkv16, one launch ----------------
__global__ __launch_bounds__(256) void rms_rope_qk(unsigned short* __restrict__ buf,
    const float* __restrict__ nwq, const float* __restrict__ nwk,
    const float* __restrict__ ct, const float* __restrict__ st){
  int row = blockIdx.x;
  int sl = blockIdx.y;
  const float* nw = sl ? nwk : nwq;
  unsigned short* xr = buf + (size_t)row*(3*DIM) + sl*DIM;
  int tid = threadIdx.x;
  float ss = 0.f; float v[6];
  #pragma unroll
  for (int i = 0; i < 6; i++){ v[i] = b2f(xr[tid + i*256]); ss += v[i]*v[i]; }
  #pragma unroll
  for (int m = 1; m < 64; m <<= 1) ss += __shfl_xor(ss, m, 64);
  __shared__ float bss[4];
  if ((tid & 63) == 0) bss[tid >> 6] = ss;
  __syncthreads();
  ss = bss[0]+bss[1]+bss[2]+bss[3];
  float inv = rsqrtf(ss*(1.f/DIM) + 1e-6f);
  int f = row/400, hp = (row/20)%20, wp = row%20;   // Fg=8, Hg=20, Wg=20
  for (int p = tid; p < 768; p += 256){
    int hh = p >> 6, j = p & 63;                     // head, freq index (c=64)
    int pos = (j < 22) ? f : ((j < 43) ? hp : wp);   // c0=22, c1=21
    float c_ = ct[pos*64 + j], s_ = st[pos*64 + j];
    int base = hh*HD + 2*j;
    float xre = b2f(xr[base])   * inv * nw[base];
    float xim = b2f(xr[base+1]) * inv * nw[base+1];
    xr[base]   = f2b(xre*c_ - xim*s_);
    xr[base+1] = f2b(xre*s_ + xim*c_);
  }
}

// ---------------- RMS norm (no rope), bf16 IN-PLACE, row stride ld ----------------
__global__ __launch_bounds__(256) void rms_rope_b16(unsigned short* __restrict__ buf, int ld,
    const float* __restrict__ nw){
  int row = blockIdx.x;
  unsigned short* xr = buf + (size_t)row*ld;
  int tid = threadIdx.x;
  float ss = 0.f; float v[6];
  #pragma unroll
  for (int i = 0; i < 6; i++){ v[i] = b2f(xr[tid + i*256]); ss += v[i]*v[i]; }
  #pragma unroll
  for (int m = 1; m < 64; m <<= 1) ss += __shfl_xor(ss, m, 64);
  __shared__ float bss[4];
  if ((tid & 63) == 0) bss[tid >> 6] = ss;
  __syncthreads();
  ss = bss[0]+bss[1]+bss[2]+bss[3];
  float inv = rsqrtf(ss*(1.f/DIM) + 1e-6f);
  #pragma unroll
  for (int i = 0; i < 6; i++){ int c = tid + i*256; xr[c] = f2b(v[i]*inv*nw[c]); }
}

// ---------------- pack V transposed per head: VT[h][d][tok]; bf16 in, row stride ld ----------------
__global__ __launch_bounds__(256) void packvt_kernel(const unsigned short* __restrict__ pre, int ld,
    unsigned short* __restrict__ VT, int ntok){
  int h = blockIdx.y; int t0 = blockIdx.x*64;
  __shared__ unsigned short tile[128][72];
  int tid = threadIdx.x;
  int d = tid & 127, tl = tid >> 7;
  #pragma unroll 4
  for (int i = 0; i < 32; i++){
    int tok = t0 + tl + 2*i;
    tile[d][tl + 2*i] = pre[(size_t)tok*ld + h*HD + d];
  }
  __syncthreads();
  int dd = tid >> 6, tl2 = tid & 63;
  #pragma unroll 4
  for (int i = 0; i < 32; i++){
    int d2 = dd + 4*i;
    VT[((size_t)h*HD + d2)*ntok + t0 + tl2] = tile[d2][tl2];
  }
}

// ---------------- split-K reduce epilogue (aliasing intentional; no __restrict__) ----------------
__global__ void reduce_f32(const float* P0, const float* P1,
    const float* bias, const float* resid,
    const float* svec, float* out, int total4){
  int i = blockIdx.x*256 + threadIdx.x;
  if (i >= total4) return;
  int col = (i*4) % DIM;
  float4 p0 = ((const float4*)P0)[i];
  float4 p1 = ((const float4*)P1)[i];
  float4 rs = ((const float4*)resid)[i];
  float4 o;
  float s0 = svec ? svec[col]   : 1.f;
  float s1 = svec ? svec[col+1] : 1.f;
  float s2 = svec ? svec[col+2] : 1.f;
  float s3 = svec ? svec[col+3] : 1.f;
  o.x = rs.x + (p0.x + p1.x + bias[col])*s0;
  o.y = rs.y + (p0.y + p1.y + bias[col+1])*s1;
  o.z = rs.z + (p0.z + p1.z + bias[col+2])*s2;
  o.w = rs.w + (p0.w + p1.w + bias[col+3])*s3;
  ((float4*)out)[i] = o;
}

// ---------------- 128x128 GEMM, 512 threads / 8 waves (4m x 2n), BK=32 (r12 proven) ----------------
__global__ __launch_bounds__(512, 4) void gemm128_kernel(const unsigned short* __restrict__ A,
    const unsigned short* __restrict__ WT, const float* __restrict__ bias,
    int M, int N, int ldA, int ksize, int ep,
    float* __restrict__ outf0, float* __restrict__ outf1, unsigned short* __restrict__ outb){
  __shared__ unsigned short As[2][128*32];
  __shared__ unsigned short Bs[2][128*32];
  int t = threadIdx.x;
  int wv = t >> 6, lane = t & 63;
  int lr = lane & 15, lk = lane >> 4;
  int gx = gridDim.x;
  int nwg = gx * gridDim.y;
  int wg = xcd_swizzle(blockIdx.y*gx + blockIdx.x, nwg);
  int m0 = (wg % gx)*128, n0 = (wg / gx)*128;
  int kbeg = blockIdx.z*ksize;
  int wm = (wv >> 1)*32, wn = (wv & 1)*64;   // 4 m-waves x 2 n-waves; 32x64 per wave
  f32x4 z = {0.f,0.f,0.f,0.f};
  f32x4 acc[2][4];
  #pragma unroll
  for (int i = 0; i < 2; i++)
    #pragma unroll
    for (int j = 0; j < 4; j++) acc[i][j] = z;

  int srow = t >> 2;
  int sslot = (t & 3) ^ (srow & 3);
  const unsigned short* Ap0 = A  + (size_t)(m0 + srow)*ldA + kbeg + sslot*8;
  const unsigned short* Bp0 = WT + (size_t)(n0 + srow)*ldA + kbeg + sslot*8;
  int slA = (lk ^ (lr & 3))*8;

  int nk = ksize >> 5;
  gload_lds16(Ap0, &As[0][wv*512]);
  gload_lds16(Bp0, &Bs[0][wv*512]);
  asm volatile("s_waitcnt vmcnt(0)" ::: "memory");
  __syncthreads();

  for (int tt = 0; tt < nk; ++tt){
    int cur = tt & 1;
    if (tt + 1 < nk){
      int kn = (tt + 1) << 5;
      gload_lds16(Ap0 + kn, &As[cur^1][wv*512]);
      gload_lds16(Bp0 + kn, &Bs[cur^1][wv*512]);
    }
    bf16x8 af[2], bfr[4];
    #pragma unroll
    for (int i = 0; i < 2; i++)
      af[i]  = *(const bf16x8*)&As[cur][(wm + i*16 + lr)*32 + slA];
    #pragma unroll
    for (int j = 0; j < 4; j++)
      bfr[j] = *(const bf16x8*)&Bs[cur][(wn + j*16 + lr)*32 + slA];
    #pragma unroll
    for (int i = 0; i < 2; i++)
      #pragma unroll
      for (int j = 0; j < 4; j++)
        acc[i][j] = mfma16(af[i], bfr[j], acc[i][j]);
    asm volatile("s_waitcnt vmcnt(0)" ::: "memory");
    __syncthreads();
  }

  float* pdst = blockIdx.z ? outf1 : outf0;
  #pragma unroll
  for (int i = 0; i < 2; i++)
    #pragma unroll
    for (int j = 0; j < 4; j++)
      #pragma unroll
      for (int r = 0; r < 4; r++){
        int row = m0 + wm + i*16 + lk*4 + r;
        int col = n0 + wn + j*16 + lr;
        size_t idx = (size_t)row*N + col;
        if (ep == 4){
          pdst[idx] = acc[i][j][r];
        } else if (ep == 3){
          outb[idx] = f2b(acc[i][j][r] + bias[col]);
        } else {
          outb[idx] = f2b(gelu_f(acc[i][j][r] + bias[col]));
        }
      }
}

// ---------------- 128x256 GEMM, 512 threads / 8 waves (2m x 4n, 64x64 each), BK=32 ----------------
__global__ __launch_bounds__(512, 4) void gemmw_kernel(const unsigned short* __restrict__ A,
    const unsigned short* __restrict__ WT, const float* __restrict__ bias,
    int M, int N, int ldA, int K, int ep, unsigned short* __restrict__ outb){
  __shared__ unsigned short As[2][128*32];
  __shared__ unsigned short Bs[2][256*32];
  int t = threadIdx.x;
  int wv = t >> 6, lane = t & 63;
  int lr = lane & 15, lk = lane >> 4;
  int gx = gridDim.x;
  int wg = xcd_swizzle(blockIdx.y*gx + blockIdx.x, gx*gridDim.y);
  int m0 = (wg % gx)*128, n0 = (wg / gx)*256;
  int wm = (wv >> 2)*64, wn = (wv & 3)*64;   // 2 m-waves x 4 n-waves; 64x64 per wave
  f32x4 z = {0.f,0.f,0.f,0.f};
  f32x4 acc[4][4];
  #pragma unroll
  for (int i = 0; i < 4; i++)
    #pragma unroll
    for (int j = 0; j < 4; j++) acc[i][j] = z;

  int srow = t >> 2;                         // 0..127
  int sslot = (t & 3) ^ (srow & 3);
  const unsigned short* Ap0 = A  + (size_t)(m0 + srow)*ldA + sslot*8;
  const unsigned short* Bp0 = WT + (size_t)(n0 + srow)*ldA + sslot*8;
  const unsigned short* Bp1 = WT + (size_t)(n0 + 128 + srow)*ldA + sslot*8;
  int slA = (lk ^ (lr & 3))*8;

  int nk = K >> 5;
  gload_lds16(Ap0, &As[0][wv*512]);
  gload_lds16(Bp0, &Bs[0][wv*512]);
  gload_lds16(Bp1, &Bs[0][4096 + wv*512]);
  asm volatile("s_waitcnt vmcnt(0)" ::: "memory");
  __syncthreads();

  for (int tt = 0; tt < nk; ++tt){
    int cur = tt & 1;
    if (tt + 1 < nk){
      int kn = (tt + 1) << 5;
      gload_lds16(Ap0 + kn, &As[cur^1][wv*512]);
      gload_lds16(Bp0 + kn, &Bs[cur^1][wv*512]);
      gload_lds16(Bp1 + kn, &Bs[cur^1][4096 + wv*512]);
    }
    bf16x8 af[4], bfr[4];
    #pragma unroll
    for (int i = 0; i < 4; i++)
      af[i]  = *(const bf16x8*)&As[cur][(wm + i*16 + lr)*32 + slA];
    #pragma unroll
    for (int j = 0; j < 4; j++)
      bfr[j] = *(const bf16x8*)&Bs[cur][(wn + j*16 + lr)*32 + slA];
    #pragma unroll
    for (int i = 0; i < 4; i++)
      #pragma unroll
      for (int j = 0; j < 4; j++)
        acc[i][j] = mfma16(af[i], bfr[j], acc[i][j]);
    asm volatile("s_waitcnt vmcnt(0)" ::: "memory");
    __syncthreads();
  }

  #pragma unroll
  for (int i = 0; i < 4; i++)
    #pragma unroll
    for (int j = 0; j < 4; j++)
      #pragma unroll
      for (int r = 0; r < 4; r++){
        int row = m0 + wm + i*16 + lk*4 + r;
        int col = n0 + wn + j*16 + lr;
        size_t idx = (size_t)row*N + col;
        float vv = acc[i][j][r] + bias[col];
        outb[idx] = (ep == 3) ? f2b(vv) : f2b(gelu_f(vv));
      }
}

// ---------------- flash attention, swapped-QK, KV-SPLIT via blockIdx.z ----------------
// gridDim.z==1: direct normalized write to O (cross-attn path).
// gridDim.z>1 : each z covers kv [z*kvchunk, z*kvchunk+kvchunk); writes normalized
// partial to op0/op1 (bf16, O layout) and per-row (m,l) to ml[(z*NH+h)*LQ + row].
__global__ __launch_bounds__(256, 3) void attn_kernel(const unsigned short* __restrict__ Q, int ldQ,
    const unsigned short* __restrict__ Kg, int ldK, const unsigned short* __restrict__ VT,
    unsigned short* O, int nkv, int vlen, int kvchunk,
    float2* ml, unsigned short* op0, unsigned short* op1){
  __shared__ unsigned short Kls[64*128];
  __shared__ unsigned short Vls[128*64];
  __shared__ unsigned short Pls[4][16][80];
  int gx = gridDim.x;
  int wg = xcd_swizzle(blockIdx.y*gx + blockIdx.x, gx*gridDim.y);
  int bq = wg % gx, h = wg / gx;
  int zi = blockIdx.z;
  int kv0 = zi*kvchunk;
  int tid = threadIdx.x;
  int wv = tid >> 6, lane = tid & 63;
  int lr = lane & 15, lk = lane >> 4;
  int q0 = bq*64 + wv*16;

  bf16x8 qf[4];
  const unsigned short* qp = Q + (size_t)(q0 + lr)*ldQ + h*HD + lk*8;
  #pragma unroll
  for (int kk = 0; kk < 4; kk++) qf[kk] = *(const bf16x8*)(qp + kk*32);

  f32x4 z = {0.f,0.f,0.f,0.f};
  f32x4 acc[8];
  #pragma unroll
  for (int d = 0; d < 8; d++) acc[d] = z;
  float mrun = -1e30f, lrun = 0.f;
  const float sc = 0.08838834764831845f;
  int swz = (lr & 7) << 4;

  for (int kt = kv0; kt < kv0 + kvchunk; kt += 64){
    __syncthreads();
    #pragma unroll
    for (int j = 0; j < 4; j++){
      int row = wv*16 + j*4 + (lane >> 4);
      int cb  = ((lane & 15)*16) ^ ((row & 7) << 4);
      gload_lds16(Kg + (size_t)(kt + row)*ldK + h*HD + (cb >> 1),
                  &Kls[(wv*16 + j*4)*128]);
    }
    #pragma unroll
    for (int j = 0; j < 4; j++){
      int d  = wv*32 + j*8 + (lane >> 3);
      int cb = ((lane & 7)*16) ^ ((d & 7) << 4);
      gload_lds16(VT + ((size_t)h*HD + d)*vlen + kt + (cb >> 1),
                  &Vls[(wv*32 + j*8)*64]);
    }
    asm volatile("s_waitcnt vmcnt(0)" ::: "memory");
    __syncthreads();

    f32x4 s[4];
    #pragma unroll
    for (int t4 = 0; t4 < 4; t4++) s[t4] = z;
    #pragma unroll
    for (int t4 = 0; t4 < 4; t4++){
      #pragma unroll
      for (int kk = 0; kk < 4; kk++){
        bf16x8 kf = *(const bf16x8*)&Kls[(t4*16 + lr)*128 + (((kk*64 + lk*16) ^ swz) >> 1)];
        s[t4] = mfma16(kf, qf[kk], s[t4]);
      }
    }

    float vv[4][4]; float pmax = -1e30f;
    #pragma unroll
    for (int t4 = 0; t4 < 4; t4++)
      #pragma unroll
      for (int r = 0; r < 4; r++){
        float xv = s[t4][r]*sc; vv[t4][r] = xv; pmax = fmaxf(pmax, xv);
      }
    pmax = fmaxf(pmax, __shfl_xor(pmax, 16, 64));
    pmax = fmaxf(pmax, __shfl_xor(pmax, 32, 64));

    if (__all(pmax - mrun <= 8.f)){
      float rs = 0.f;
      #pragma unroll
      for (int t4 = 0; t4 < 4; t4++)
        #pragma unroll
        for (int r = 0; r < 4; r++){
          float pv = __expf(vv[t4][r] - mrun); vv[t4][r] = pv; rs += pv;
        }
      rs += __shfl_xor(rs, 16, 64);
      rs += __shfl_xor(rs, 32, 64);
      lrun += rs;
    } else {
      float mn = fmaxf(mrun, pmax);
      float cr = __expf(mrun - mn);
      mrun = mn;
      float rs = 0.f;
      #pragma unroll
      for (int t4 = 0; t4 < 4; t4++)
        #pragma unroll
        for (int r = 0; r < 4; r++){
          float pv = __expf(vv[t4][r] - mn); vv[t4][r] = pv; rs += pv;
        }
      rs += __shfl_xor(rs, 16, 64);
      rs += __shfl_xor(rs, 32, 64);
      lrun = lrun*cr + rs;
      #pragma unroll
      for (int d = 0; d < 8; d++) acc[d] *= cr;
    }

    #pragma unroll
    for (int t4 = 0; t4 < 4; t4++){
      *(unsigned*)&Pls[wv][lr][t4*16 + lk*4]     = pack2(vv[t4][0], vv[t4][1]);
      *(unsigned*)&Pls[wv][lr][t4*16 + lk*4 + 2] = pack2(vv[t4][2], vv[t4][3]);
    }
    bf16x8 pb0 = *(const bf16x8*)&Pls[wv][lr][lk*8];
    bf16x8 pb1 = *(const bf16x8*)&Pls[wv][lr][32 + lk*8];

    #pragma unroll
    for (int db = 0; db < 8; db++){
      bf16x8 vf0 = *(const bf16x8*)&Vls[(db*16 + lr)*64 + (((lk*16) ^ swz) >> 1)];
      acc[db] = mfma16(vf0, pb0, acc[db]);
      bf16x8 vf1 = *(const bf16x8*)&Vls[(db*16 + lr)*64 + (((64 + lk*16) ^ swz) >> 1)];
      acc[db] = mfma16(vf1, pb1, acc[db]);
    }
  }

  float inv = 1.f/lrun;
  unsigned short* od = (gridDim.z == 1) ? O : (zi ? op1 : op0);
  unsigned short* op = od + (size_t)(q0 + lr)*DIM + h*HD + lk*4;
  #pragma unroll
  for (int db = 0; db < 8; db++){
    u16x4 ov;
    ov[0] = f2b(acc[db][0]*inv); ov[1] = f2b(acc[db][1]*inv);
    ov[2] = f2b(acc[db][2]*inv); ov[3] = f2b(acc[db][3]*inv);
    *(u16x4*)(op + db*16) = ov;
  }
  if (gridDim.z > 1 && lk == 0)
    ml[((size_t)zi*NH + h)*LQ + (q0 + lr)] = make_float2(mrun, lrun);
}

// ---------------- combine 2 KV-split partials: O = a0*O0 + a1*O1 per head ----------------
__global__ __launch_bounds__(256) void attn_combine(const unsigned short* __restrict__ op0,
    const unsigned short* __restrict__ op1, const float2* __restrict__ ml,
    unsigned short* __restrict__ O){
  int row = blockIdx.x;
  int tid = threadIdx.x;
  __shared__ float w0s[NH], w1s[NH];
  if (tid < NH){
    float2 a = ml[(size_t)tid*LQ + row];
    float2 b = ml[((size_t)NH + tid)*LQ + row];
    float ms = fmaxf(a.x, b.x);
    float e0 = __expf(a.x - ms)*a.y;
    float e1 = __expf(b.x - ms)*b.y;
    float inv = 1.f/(e0 + e1);
    w0s[tid] = e0*inv; w1s[tid] = e1*inv;
  }
  __syncthreads();
  size_t base = (size_t)row*DIM;
  #pragma unroll
  for (int i = 0; i < 2; i++){
    int c4 = tid + i*256;
    if (c4 < 384){
      int h = c4 >> 5;                       // (c4*4)/128
      u16x4 a = *(const u16x4*)(op0 + base + c4*4);
      u16x4 b = *(const u16x4*)(op1 + base + c4*4);
      u16x4 o;
      #pragma unroll
      for (int j = 0; j < 4; j++)
        o[j] = f2b(b2f(a[j])*w0s[h] + b2f(b[j])*w1s[h]);
      *(u16x4*)(O + base + c4*4) = o;
    }
  }
}

// ---------------- host launch ----------------

extern "C" void kernel_launch(void* const* d_in, const int* in_sizes, int n_in,
                              void* d_out, int out_size, void* d_ws, size_t ws_size,
                              hipStream_t stream){
  const float* x    = (const float*)d_in[0];
  const float* e    = (const float*)d_in[1];
  const float* ctx  = (const float*)d_in[2];
  const float* fcos = (const float*)d_in[3];
  const float* fsin = (const float*)d_in[4];
  const float* modu = (const float*)d_in[5];
  const float* sa_qw = (const float*)d_in[6];  const float* sa_qb = (const float*)d_in[7];
  const float* sa_kw = (const float*)d_in[8];  const float* sa_kb = (const float*)d_in[9];
  const float* sa_vw = (const float*)d_in[10]; const float* sa_vb = (const float*)d_in[11];
  const float* sa_ow = (const float*)d_in[12]; const float* sa_ob = (const float*)d_in[13];
  const float* sa_nq = (const float*)d_in[14]; const float* sa_nk = (const float*)d_in[15];
  const float* ca_qw = (const float*)d_in[16]; const float* ca_qb = (const float*)d_in[17];
  const float* ca_kw = (const float*)d_in[18]; const float* ca_kb = (const float*)d_in[19];
  const float* ca_vw = (const float*)d_in[20]; const float* ca_vb = (const float*)d_in[21];
  const float* ca_ow = (const float*)d_in[22]; const float* ca_ob = (const float*)d_in[23];
  const float* ca_nq = (const float*)d_in[24]; const float* ca_nk = (const float*)d_in[25];
  const float* n3w = (const float*)d_in[26]; const float* n3b = (const float*)d_in[27];
  const float* fw1 = (const float*)d_in[28]; const float* fb1 = (const float*)d_in[29];
  const float* fw2 = (const float*)d_in[30]; const float* fb2 = (const float*)d_in[31];

  char* p = (char*)d_ws;
  auto alloc = [&](size_t bytes){ void* r = (void*)p; p += (bytes + 255) & ~(size_t)255; return r; };
  unsigned short* wt[8];
  for (int i = 0; i < 8; i++) wt[i] = (unsigned short*)alloc((size_t)DIM*DIM*2);
  unsigned short* wtf1 = (unsigned short*)alloc((size_t)FFN*DIM*2);   // dead after FFN1
  unsigned short* wtf2 = (unsigned short*)alloc((size_t)DIM*FFN*2);
  float* em     = (float*)alloc(6*DIM*4);
  float* qkvb   = (float*)alloc(3*DIM*4);
  float* ckvb   = (float*)alloc(2*DIM*4);
  float2* mlb   = (float2*)alloc((size_t)2*NH*LQ*sizeof(float2));
  unsigned short* nbuf = (unsigned short*)alloc((size_t)LQ*DIM*2);
  // dead-chain for FFN overlay: qkv16+VTb+Qb+Ob = 59.0M >= 57.3M
  unsigned short* qkv16 = (unsigned short*)alloc((size_t)LQ*3*DIM*2);   // [3200][4608]
  unsigned short* VTb   = (unsigned short*)alloc((size_t)LQ*DIM*2);
  unsigned short* Qb    = (unsigned short*)alloc((size_t)LQ*DIM*2);
  unsigned short* Ob    = (unsigned short*)alloc((size_t)LQ*DIM*2);
  float* x1 = (float*)alloc((size_t)LQ*DIM*4);
  unsigned short* ctxb   = (unsigned short*)alloc((size_t)LKV*DIM*2);
  unsigned short* cakv16 = (unsigned short*)alloc((size_t)LKV*2*DIM*2); // [512][3072]

  float* P0   = (float*)d_out;        // scratch until its branch's reduce
  float* P1a  = (float*)qkv16;        // 19.66M partial (qkv16 dead at use sites)
  float* P1f  = (float*)wtf1;         // FFN2 partial (wtf1 dead after FFN1)
  unsigned short* hbuf = qkv16;       // FFN hidden [3200][8960] over dead chain
  // self-attn KV-split partials: Qb (z=0) and x1 bytes (z=1) — both dead until combine
  unsigned short* opz0 = Qb;
  unsigned short* opz1 = (unsigned short*)x1;
  const int TOT4 = LQ*DIM/4;

  // prep
  add_vec<<<36, 256, 0, stream>>>(modu, e, em, 6*DIM);
  concat3<<<18, 256, 0, stream>>>(sa_qb, sa_kb, sa_vb, qkvb, DIM);
  concat3<<<12, 256, 0, stream>>>(ca_kb, ca_vb, ca_vb, ckvb, DIM);
  const float* wsrc[8] = {sa_qw, sa_kw, sa_vw, sa_ow, ca_qw, ca_kw, ca_vw, ca_ow};
  for (int i = 0; i < 8; i++)
    transpose_conv<<<dim3(48,48), dim3(32,8), 0, stream>>>(wsrc[i], wt[i], DIM, DIM);
  transpose_conv<<<dim3(280,48), dim3(32,8), 0, stream>>>(fw1, wtf1, DIM, FFN);
  transpose_conv<<<dim3(48,280), dim3(32,8), 0, stream>>>(fw2, wtf2, FFN, DIM);
  convert_bf16<<<(LKV*DIM)/256, 256, 0, stream>>>(ctx, ctxb, LKV*DIM);

  // ---- self-attention branch ----
  ln_mod_kernel<<<LQ, 256, 0, stream>>>(x, em + DIM, em, 1, nbuf);
  gemmw_kernel<<<dim3(25,18), 512, 0, stream>>>(nbuf, wt[0], qkvb, LQ, 3*DIM, DIM, DIM, 3, qkv16);
  rms_rope_qk<<<dim3(LQ,2), 256, 0, stream>>>(qkv16, sa_nq, sa_nk, fcos, fsin);
  packvt_kernel<<<dim3(50,12), 256, 0, stream>>>(qkv16 + 2*DIM, 3*DIM, VTb, LQ);
  attn_kernel<<<dim3(50,12,2), 256, 0, stream>>>(qkv16, 3*DIM, qkv16 + DIM, 3*DIM, VTb,
                                                 nullptr, LQ, LQ, LQ/2, mlb, opz0, opz1);
  attn_combine<<<LQ, 256, 0, stream>>>(opz0, opz1, mlb, Ob);
  gemm128_kernel<<<dim3(25,12,2), 512, 0, stream>>>(Ob, wt[3], nullptr, LQ, DIM, DIM, DIM/2, 4,
                                                    P0, P1a, nullptr);
  reduce_ln_kernel<<<LQ, 256, 0, stream>>>(P0, P1a, sa_ob, x, em + 2*DIM, x1,
                                           n3w, n3b, 0, nbuf);

  // ---- cross-attention branch ----
  gemm128_kernel<<<dim3(25,12,2), 512, 0, stream>>>(nbuf, wt[4], nullptr, LQ, DIM, DIM, DIM/2, 4,
                                                    P0, P1a, nullptr);
  reduce_rms_kernel<<<LQ, 256, 0, stream>>>(P0, P1a, ca_qb, ca_nq, Qb);
  gemm128_kernel<<<dim3(4,24,1), 512, 0, stream>>>(ctxb, wt[5], ckvb, LKV, 2*DIM, DIM, DIM, 3,
                                                   nullptr, nullptr, cakv16);
  rms_rope_b16<<<LKV, 256, 0, stream>>>(cakv16, 2*DIM, ca_nk);
  packvt_kernel<<<dim3(8,12), 256, 0, stream>>>(cakv16 + DIM, 2*DIM, VTb, LKV);
  attn_kernel<<<dim3(50,12,1), 256, 0, stream>>>(Qb, DIM, cakv16, 2*DIM, VTb,
                                                 Ob, LKV, LKV, LKV, nullptr, nullptr, nullptr);
  gemm128_kernel<<<dim3(25,12,2), 512, 0, stream>>>(Ob, wt[7], nullptr, LQ, DIM, DIM, DIM/2, 4,
                                                    P0, P1a, nullptr);
  reduce_ln_kernel<<<LQ, 256, 0, stream>>>(P0, P1a, ca_ob, x1, nullptr, x1,
                                           em + 4*DIM, em + 3*DIM, 1, nbuf);

  // ---- FFN branch ----
  gemmw_kernel<<<dim3(25,35), 512, 0, stream>>>(nbuf, wtf1, fb1, LQ, FFN, DIM, DIM, 2, hbuf);
  gemm128_kernel<<<dim3(25,12,2), 512, 0, stream>>>(hbuf, wtf2, nullptr, LQ, DIM, FFN, FFN/2, 4,
                                                    P0, P1f, nullptr);
  reduce_f32<<<(TOT4+255)/256, 256, 0, stream>>>(P0, P1f, fb2, x1, em + 5*DIM, (float*)d_out, TOT4);
}